// Round 9
// baseline (90.082 us; speedup 1.0000x reference)
//
#include <hip/hip_runtime.h>
#include <math.h>

#define BATCH 8
#define NPRI  4096
#define TOPK  200

typedef unsigned long long u64;
typedef unsigned int u32;

#define WS_SOA (BATCH * NPRI)  // floats per SoA array

// correctly-rounded f32 exp via f64 (matches numpy float32 exp bit-exactly)
__device__ __forceinline__ float exp_f32_cr(float x) { return (float)exp((double)x); }

// ---------------------------------------------------------------------------
// K1: fused key + counting-rank sort + decode + scatter.
// 256 blocks (32/image), 256 thr. Block computes ALL 4096 softmax keys of its
// image into LDS (1 exp per key: softmax-of-2 has exp(0)=1 on the max side),
// then ranks its 128-i tile with G=8 register i-keys over 16 j-ranges
// (256 keys each): 512 ds_read_b128/CU (4-way broadcast, 1.58x) ~4us, VALU
// ~9K cyc overlapped. Tile-0 blocks also zero their image's output slice.
// ---------------------------------------------------------------------------
__global__ __launch_bounds__(256) void rank_decode_kernel(
    const float* __restrict__ loc, const float* __restrict__ conf,
    const float* __restrict__ prior, float* __restrict__ ws,
    float* __restrict__ out) {
  __shared__ u64 sk[NPRI];         // 32 KB: this image's keys
  __shared__ u32 prank[16][128];   // 8 KB: per-range partial ranks
  const int blk = blockIdx.x;
  const int b = blk >> 5;          // 32 blocks per image
  const int tile = blk & 31;       // 128-wide i-tile
  const int t = threadIdx.x;
  const int rg = t >> 4;           // j-range 0..15 (256 keys each)
  const int ig = t & 15;           // i-octet (i = tile*128 + ig*8 + 0..7)

  // zero this image's output slice (harness poisons d_out before every call)
  if (tile == 0) {
    float* slice = out + (size_t)b * 2 * TOPK * 5;
    for (int p = t; p < 2 * TOPK * 5; p += 256) slice[p] = 0.0f;
  }

  // ---- keys: softmax -> (~score_bits)<<32 | idx  (stable argsort(-s)) ----
  // bit-exact to ref: m=max(c0,c1); a0=c0-m, a1=c1-m (one is +0.0);
  // e=exp(a0+a1) (exact since x+0=x); e0+e1 == e+1 (fadd commutes);
  // s = c1>=c0 ? 1/(e+1) : e/(1+e)  == fdiv(e1, fadd(e0,e1)) bitwise.
  {
    const float2* cf = (const float2*)conf + b * NPRI;
#pragma unroll 4
    for (int g = t; g < NPRI; g += 256) {
      float2 c = cf[g];
      float m  = fmaxf(c.x, c.y);
      float a  = __fadd_rn(__fsub_rn(c.x, m), __fsub_rn(c.y, m));
      float e  = exp_f32_cr(a);
      float s  = (c.y >= c.x) ? __fdiv_rn(1.0f, __fadd_rn(e, 1.0f))
                              : __fdiv_rn(e, __fadd_rn(1.0f, e));
      sk[g] = ((u64)(~__float_as_uint(s)) << 32) | (u32)g;
    }
  }
  __syncthreads();

  // ---- rank: G=8 i-keys vs 256-key j-range stream ----
  const ulonglong2* sk2 = (const ulonglong2*)sk;
  u64 K[8];
#pragma unroll
  for (int q = 0; q < 4; ++q) {
    ulonglong2 p = sk2[tile * 64 + ig * 4 + q];
    K[2 * q] = p.x; K[2 * q + 1] = p.y;
  }
  u32 C[8] = {0, 0, 0, 0, 0, 0, 0, 0};
  {
    const int r0 = rg * 128;  // 128 ulonglong2 = 256 keys per range
#pragma unroll 2
    for (int r = r0; r < r0 + 128; ++r) {
      ulonglong2 kk = sk2[r];
#pragma unroll
      for (int q = 0; q < 8; ++q) {
        C[q] += (kk.x < K[q]);
        C[q] += (kk.y < K[q]);
      }
    }
  }
  ((uint4*)prank[rg])[ig * 2 + 0] = make_uint4(C[0], C[1], C[2], C[3]);
  ((uint4*)prank[rg])[ig * 2 + 1] = make_uint4(C[4], C[5], C[6], C[7]);
  __syncthreads();

  // ---- decode + scatter (threads 0..127, coalesced loc/prior reads) ----
  if (t < 128) {
    int rank = 0;
#pragma unroll
    for (int q = 0; q < 16; ++q) rank += (int)prank[q][t];
    const int ig2 = tile * 128 + t;  // original index within image
    const u64 myk = sk[ig2];
    const float s = __uint_as_float(~(u32)(myk >> 32));
    const float4 l = ((const float4*)loc)[b * NPRI + ig2];
    const float4 pq = ((const float4*)prior)[ig2];
    float cx = __fadd_rn(pq.x, __fmul_rn(__fmul_rn(l.x, 0.1f), pq.z));
    float cy = __fadd_rn(pq.y, __fmul_rn(__fmul_rn(l.y, 0.1f), pq.w));
    float w  = __fmul_rn(pq.z, exp_f32_cr(__fmul_rn(l.z, 0.2f)));
    float h  = __fmul_rn(pq.w, exp_f32_cr(__fmul_rn(l.w, 0.2f)));
    float hw = __fmul_rn(w, 0.5f), hh = __fmul_rn(h, 0.5f);
    float x1 = __fsub_rn(cx, hw), x2 = __fadd_rn(cx, hw);
    float y1 = __fsub_rn(cy, hh), y2 = __fadd_rn(cy, hh);
    const int o = b * NPRI + rank;
    float* sx1 = ws;
    float* sy1 = ws + 1 * WS_SOA;
    float* sx2 = ws + 2 * WS_SOA;
    float* sy2 = ws + 3 * WS_SOA;
    float* sar = ws + 4 * WS_SOA;
    float* ssc = ws + 5 * WS_SOA;
    sx1[o] = x1; sy1[o] = y1; sx2[o] = x2; sy2[o] = y2;
    sar[o] = __fmul_rn(__fsub_rn(x2, x1), __fsub_rn(y2, y1));
    ssc[o] = s;
  }
}

// ---------------------------------------------------------------------------
// K2: lazy-mask greedy NMS (verified logic), 8 waves/block, 2 barriers/chunk.
// Next chunk's bx/ba staging (wave 1, from prefetch regs) overlaps wave 0's
// serial resolve. One block per image.
// ---------------------------------------------------------------------------
__global__ __launch_bounds__(512) void nms_scan_kernel(const float* __restrict__ ws,
                                                       float* __restrict__ out) {
  __shared__ float4 kbox[TOPK];
  __shared__ float  karea[TOPK];
  __shared__ float4 bx[64];
  __shared__ float  ba[64];
  __shared__ u64 diag[64];
  __shared__ u64 parts[8];
  __shared__ int klist[TOPK];
  __shared__ int s_kcnt, s_cnt, s_stop, s_total;

  const int b = blockIdx.x, t = threadIdx.x, lane = t & 63, wv = t >> 6;
  const float* sx1 = ws;
  const float* sy1 = ws + 1 * WS_SOA;
  const float* sx2 = ws + 2 * WS_SOA;
  const float* sy2 = ws + 3 * WS_SOA;
  const float* sar = ws + 4 * WS_SOA;
  const float* ssc = ws + 5 * WS_SOA;
  // exact threshold: fl(inter/uni) > 0.45f  <=>  inter > M*uni (exact in f64)
  const double M = 0.5 * ((double)0.45f + (double)__uint_as_float(0x3EE66667u));

  if (t == 0) { s_kcnt = 0; s_cnt = 0; s_stop = 0; s_total = 0; }

  // prefetch chunk 0 (each thread holds col (0,lane); L1-served redundancy)
  int o_n = b * NPRI + lane;
  float nx1 = sx1[o_n], ny1 = sy1[o_n], nx2 = sx2[o_n], ny2 = sy2[o_n];
  float nar = sar[o_n], nsc = ssc[o_n];
  if (wv == 0) { bx[lane] = make_float4(nx1, ny1, nx2, ny2); ba[lane] = nar; }
  __syncthreads();

  for (int c = 0; c < 64; ++c) {
    const int col = c * 64 + lane, o = b * NPRI + col;
    const float x1 = nx1, y1 = ny1, x2 = nx2, y2 = ny2, ar = nar, sc = nsc;
    // issue next chunk's loads early (in flight during phases 1-3)
    if (c + 1 < 64) {
      const int on = o + 64;
      nx1 = sx1[on]; ny1 = sy1[on]; nx2 = sx2[on]; ny2 = sy2[on];
      nar = sar[on]; nsc = ssc[on];
    }
    const int kcnt = s_kcnt;  // stable since previous chunk's final barrier

    // phase 1: suppression of my column by previously-kept boxes (8-way split)
    bool supp = false;
    for (int k = wv; k < kcnt; k += 8) {
      float4 kb = kbox[k]; float ka = karea[k];
      float iw = fmaxf(__fsub_rn(fminf(kb.z, x2), fmaxf(kb.x, x1)), 0.0f);
      float ih = fmaxf(__fsub_rn(fminf(kb.w, y2), fmaxf(kb.y, y1)), 0.0f);
      float inter = __fmul_rn(iw, ih);
      float uni   = __fsub_rn(__fadd_rn(ka, ar), inter);
      if ((double)inter > M * (double)uni) { supp = true; break; }
    }
    u64 bw = __ballot(supp);
    if (lane == 0) parts[wv] = bw;

    // phase 2: diagonal rows 8wv..8wv+7 (row r vs all 64 cols of chunk)
#pragma unroll
    for (int r = 8 * wv; r < 8 * wv + 8; ++r) {
      float4 rb = bx[r]; float ra = ba[r];
      float iw = fmaxf(__fsub_rn(fminf(rb.z, x2), fmaxf(rb.x, x1)), 0.0f);
      float ih = fmaxf(__fsub_rn(fminf(rb.w, y2), fmaxf(rb.y, y1)), 0.0f);
      float inter = __fmul_rn(iw, ih);
      float uni   = __fsub_rn(__fadd_rn(ra, ar), inter);
      u64 dw = __ballot((double)inter > M * (double)uni);
      if (lane == 0) diag[r] = dw;
    }
    __syncthreads();

    // phase 3 (wave 0): serial resolve. wave 1: stage next chunk's bx/ba
    // (reads only its own prefetch regs; bx stable for phase 2 until here).
    if (wv == 1 && c + 1 < 64) {
      bx[lane] = make_float4(nx1, ny1, nx2, ny2);
      ba[lane] = nar;
    }
    if (wv == 0) {
      u64 vm = __ballot(sc > 0.01f);
      int cnt = s_cnt;
      bool stop = false;
      if (vm == 0) {
        stop = true;  // sorted desc: nothing valid beyond here
      } else {
        u64 rw = parts[0] | parts[1] | parts[2] | parts[3] |
                 parts[4] | parts[5] | parts[6] | parts[7];
        u64 ck = 0;
        for (int g = 0; g < 64; g += 8) {
          u64 d[8];
#pragma unroll
          for (int q = 0; q < 8; ++q) d[q] = diag[g + q];
#pragma unroll
          for (int q = 0; q < 8; ++q) {
            u64 kbit = ((vm & ~rw) >> (g + q)) & 1ull;
            rw |= d[q] & (0ull - kbit);
            ck |= kbit << (g + q);
          }
        }
        if ((ck >> lane) & 1ull) {
          int pos = cnt + __popcll(ck & ((1ull << lane) - 1ull));
          if (pos < TOPK) {
            klist[pos] = col;
            kbox[pos] = make_float4(x1, y1, x2, y2);
            karea[pos] = ar;
          }
        }
        cnt += __popcll(ck);
        if (cnt >= TOPK) stop = true;
      }
      if (lane == 0) {
        int capped = cnt < TOPK ? cnt : TOPK;
        s_kcnt = capped; s_cnt = cnt; s_total = capped; s_stop = stop ? 1 : 0;
      }
    }
    __syncthreads();
    if (s_stop) break;
  }

  const int total = s_total;
  for (int p = t; p < total; p += 512) {
    int i = klist[p];
    int o = b * NPRI + i;
    float* dst = out + (((size_t)b * 2 + 1) * TOPK + p) * 5;
    dst[0] = ssc[o]; dst[1] = sx1[o]; dst[2] = sy1[o]; dst[3] = sx2[o]; dst[4] = sy2[o];
  }
}

// ---------------------------------------------------------------------------
extern "C" void kernel_launch(void* const* d_in, const int* in_sizes, int n_in,
                              void* d_out, int out_size, void* d_ws, size_t ws_size,
                              hipStream_t stream) {
  const float* loc   = (const float*)d_in[0];
  const float* conf  = (const float*)d_in[1];
  const float* prior = (const float*)d_in[2];
  float* out = (float*)d_out;
  float* ws  = (float*)d_ws;

  rank_decode_kernel<<<256, 256, 0, stream>>>(loc, conf, prior, ws, out);
  nms_scan_kernel<<<BATCH, 512, 0, stream>>>(ws, out);
}